// Round 1
// baseline (851.300 us; speedup 1.0000x reference)
//
#include <hip/hip_runtime.h>
#include <hip/hip_bf16.h>

#define N_IN   128
#define N_H    4
#define N_D    32
#define N_HD   128      // H*D
#define NEG_SLOPE 0.2f

// ---------- order-preserving float<->uint for atomicMax ----------
__device__ __forceinline__ unsigned enc_f(float x) {
    unsigned u = __float_as_uint(x);
    return (u & 0x80000000u) ? ~u : (u | 0x80000000u);
}
__device__ __forceinline__ float dec_f(unsigned u) {
    return (u & 0x80000000u) ? __uint_as_float(u & 0x7FFFFFFFu) : __uint_as_float(~u);
}

// ---------- 1) feat_src = feat @ W_fc^T  (n,128)x(128,128)^T ----------
#define PR_ROWS 16
__global__ __launch_bounds__(256) void k_proj(const float* __restrict__ feat,
                                              const float* __restrict__ Wfc,
                                              float* __restrict__ fsrc, int n) {
    // W[c][k] stored at wt[c*128 + (k ^ ((c&7)<<2))] -> b128 reads conflict-free
    __shared__ float wt[128 * 128];
    __shared__ float fs[PR_ROWS * 128];
    const int t = threadIdx.x;
    for (int idx = t; idx < 128 * 128; idx += 256) {
        int cc = idx >> 7, kk = idx & 127;
        wt[cc * 128 + (kk ^ ((cc & 7) << 2))] = Wfc[idx];
    }
    const int c0 = t & 63;        // col
    const int rq = t >> 6;        // 0..3 row group
    const int sw = (c0 & 7) << 2; // same for c0+64
    const int nchunks = (n + PR_ROWS - 1) / PR_ROWS;
    for (int chunk = blockIdx.x; chunk < nchunks; chunk += gridDim.x) {
        const int base = chunk * PR_ROWS;
        __syncthreads();
        #pragma unroll
        for (int j = 0; j < PR_ROWS * 128 / 256; ++j) {
            int idx = t + j * 256;
            int r = idx >> 7, k = idx & 127;
            fs[idx] = (base + r < n) ? feat[(size_t)(base + r) * 128 + k] : 0.f;
        }
        __syncthreads();
        float acc[4][2];
        #pragma unroll
        for (int i = 0; i < 4; ++i) { acc[i][0] = 0.f; acc[i][1] = 0.f; }
        #pragma unroll 8
        for (int kq = 0; kq < 32; ++kq) {
            int k4 = kq * 4;
            float4 w0 = *(const float4*)&wt[c0 * 128 + (k4 ^ sw)];
            float4 w1 = *(const float4*)&wt[(c0 + 64) * 128 + (k4 ^ sw)];
            #pragma unroll
            for (int i = 0; i < 4; ++i) {
                float4 f = *(const float4*)&fs[(rq + 4 * i) * 128 + k4];
                acc[i][0] = fmaf(f.x, w0.x, acc[i][0]);
                acc[i][0] = fmaf(f.y, w0.y, acc[i][0]);
                acc[i][0] = fmaf(f.z, w0.z, acc[i][0]);
                acc[i][0] = fmaf(f.w, w0.w, acc[i][0]);
                acc[i][1] = fmaf(f.x, w1.x, acc[i][1]);
                acc[i][1] = fmaf(f.y, w1.y, acc[i][1]);
                acc[i][1] = fmaf(f.z, w1.z, acc[i][1]);
                acc[i][1] = fmaf(f.w, w1.w, acc[i][1]);
            }
        }
        #pragma unroll
        for (int i = 0; i < 4; ++i) {
            int r = base + rq + 4 * i;
            if (r < n) {
                fsrc[(size_t)r * 128 + c0]      = acc[i][0];
                fsrc[(size_t)r * 128 + c0 + 64] = acc[i][1];
            }
        }
    }
}

// ---------- 2) el/er per (node, head) ----------
__global__ void k_node(const float* __restrict__ fsrc, const float* __restrict__ attn_l,
                       const float* __restrict__ attn_r, const int* __restrict__ ntype,
                       float* __restrict__ el, float* __restrict__ er, int nh) {
    int t = blockIdx.x * blockDim.x + threadIdx.x;
    if (t >= nh) return;
    int nid = t >> 2, h = t & 3;
    int nt = ntype[nid];
    const float4* f4 = (const float4*)(fsrc + (size_t)nid * 128 + h * 32);
    const float4* l4 = (const float4*)(attn_l + ((size_t)nt * 4 + h) * 32);
    const float4* r4 = (const float4*)(attn_r + ((size_t)nt * 4 + h) * 32);
    float sl = 0.f, sr = 0.f;
    #pragma unroll
    for (int j = 0; j < 8; ++j) {
        float4 f = f4[j], l = l4[j], r = r4[j];
        sl += f.x * l.x + f.y * l.y + f.z * l.z + f.w * l.w;
        sr += f.x * r.x + f.y * r.y + f.z * r.z + f.w * r.w;
    }
    el[t] = sl;
    er[t] = sr;
}

// ---------- 3) ee table: only ET*H distinct values ----------
__global__ void k_ee(const float* __restrict__ W_e, const float* __restrict__ edge_emb,
                     const float* __restrict__ attn_e, float* __restrict__ eet) {
    int t = threadIdx.x;
    if (t >= 8 * 4) return;
    int et = t >> 2, h = t & 3;
    float ee = 0.f;
    for (int f = 0; f < 32; ++f) {
        float acc = 0.f;
        for (int g = 0; g < 32; ++g)
            acc += W_e[((size_t)h * 32 + f) * 32 + g] * edge_emb[et * 32 + g];
        ee += acc * attn_e[((size_t)et * 4 + h) * 32 + f];
    }
    eet[t] = ee * (float)et;
}

// ---------- 4) edge scores + leaky relu + segment max ----------
__global__ void k_escore(const int* __restrict__ src, const int* __restrict__ dst,
                         const int* __restrict__ etype, const float* __restrict__ el,
                         const float* __restrict__ er, const float* __restrict__ eet,
                         float* __restrict__ aBuf, unsigned* __restrict__ menc, int ne) {
    int e = blockIdx.x * blockDim.x + threadIdx.x;
    if (e >= ne) return;
    int s = src[e], d = dst[e], et = etype[e];
    float4 l = *(const float4*)(el + (size_t)s * 4);
    float4 r = *(const float4*)(er + (size_t)d * 4);
    float4 te = *(const float4*)(eet + (size_t)et * 4);
    float4 v;
    v.x = l.x + r.x + te.x;
    v.y = l.y + r.y + te.y;
    v.z = l.z + r.z + te.z;
    v.w = l.w + r.w + te.w;
    v.x = v.x > 0.f ? v.x : NEG_SLOPE * v.x;
    v.y = v.y > 0.f ? v.y : NEG_SLOPE * v.y;
    v.z = v.z > 0.f ? v.z : NEG_SLOPE * v.z;
    v.w = v.w > 0.f ? v.w : NEG_SLOPE * v.w;
    *(float4*)(aBuf + (size_t)e * 4) = v;
    atomicMax(menc + (size_t)d * 4 + 0, enc_f(v.x));
    atomicMax(menc + (size_t)d * 4 + 1, enc_f(v.y));
    atomicMax(menc + (size_t)d * 4 + 2, enc_f(v.z));
    atomicMax(menc + (size_t)d * 4 + 3, enc_f(v.w));
}

// ---------- 5) ex = exp(e - m[dst]); den += ex ----------
__global__ void k_eexp(const int* __restrict__ dst, const unsigned* __restrict__ menc,
                       float* __restrict__ aBuf, float* __restrict__ den, int ne) {
    int e = blockIdx.x * blockDim.x + threadIdx.x;
    if (e >= ne) return;
    int d = dst[e];
    float4 v = *(const float4*)(aBuf + (size_t)e * 4);
    uint4 mu = *(const uint4*)(menc + (size_t)d * 4);
    float4 ex;
    ex.x = __expf(v.x - dec_f(mu.x));
    ex.y = __expf(v.y - dec_f(mu.y));
    ex.z = __expf(v.z - dec_f(mu.z));
    ex.w = __expf(v.w - dec_f(mu.w));
    *(float4*)(aBuf + (size_t)e * 4) = ex;
    atomicAdd(den + (size_t)d * 4 + 0, ex.x);
    atomicAdd(den + (size_t)d * 4 + 1, ex.y);
    atomicAdd(den + (size_t)d * 4 + 2, ex.z);
    atomicAdd(den + (size_t)d * 4 + 3, ex.w);
}

// ---------- 6) a = ex / den[dst]  (final a output) ----------
__global__ void k_norm(const int* __restrict__ dst, const float* __restrict__ den,
                       float* __restrict__ aBuf, int ne) {
    int e = blockIdx.x * blockDim.x + threadIdx.x;
    if (e >= ne) return;
    int d = dst[e];
    float4 ex = *(const float4*)(aBuf + (size_t)e * 4);
    float4 dn = *(const float4*)(den + (size_t)d * 4);
    ex.x /= dn.x;
    ex.y /= dn.y;
    ex.z /= dn.z;
    ex.w /= dn.w;
    *(float4*)(aBuf + (size_t)e * 4) = ex;
}

// ---------- 7) rst[dst] += a * feat_src[src]  (atomic scatter) ----------
__global__ __launch_bounds__(256) void k_agg(const int* __restrict__ src,
                                             const int* __restrict__ dst,
                                             const float* __restrict__ aBuf,
                                             const float* __restrict__ fsrc,
                                             float* __restrict__ rst, int ne) {
    int t = threadIdx.x;
    int e = blockIdx.x * 2 + (t >> 7);
    if (e >= ne) return;
    int j = t & 127;
    int s = src[e], d = dst[e];
    float a = aBuf[(size_t)e * 4 + (j >> 5)];
    float v = fsrc[(size_t)s * 128 + j];
    atomicAdd(rst + (size_t)d * 128 + j, a * v);
}

extern "C" void kernel_launch(void* const* d_in, const int* in_sizes, int n_in,
                              void* d_out, int out_size, void* d_ws, size_t ws_size,
                              hipStream_t stream) {
    const float* feat     = (const float*)d_in[0];
    const float* W_fc     = (const float*)d_in[1];
    const float* W_e      = (const float*)d_in[2];
    const float* edge_emb = (const float*)d_in[3];
    const float* attn_l   = (const float*)d_in[4];
    const float* attn_r   = (const float*)d_in[5];
    const float* attn_e   = (const float*)d_in[6];
    const int* src   = (const int*)d_in[7];
    const int* dst   = (const int*)d_in[8];
    const int* etype = (const int*)d_in[9];
    const int* ntype = (const int*)d_in[10];
    const int n  = in_sizes[0] / N_IN;
    const int ne = in_sizes[7];

    // workspace layout (floats)
    float* ws    = (float*)d_ws;
    float* fsrc  = ws;                               // n*128
    float* el    = fsrc + (size_t)n * 128;           // n*4
    float* er    = el + (size_t)n * 4;               // n*4
    float* den   = er + (size_t)n * 4;               // n*4
    unsigned* menc = (unsigned*)(den + (size_t)n * 4); // n*4
    float* eet   = (float*)(menc + (size_t)n * 4);   // 32

    float* rst  = (float*)d_out;                     // n*128
    float* aBuf = rst + (size_t)n * 128;             // ne*4 (scratch -> final a)

    hipMemsetAsync(den, 0, (size_t)n * 8 * sizeof(float), stream);   // den + menc
    hipMemsetAsync(rst, 0, (size_t)n * 128 * sizeof(float), stream);

    k_proj<<<512, 256, 0, stream>>>(feat, W_fc, fsrc, n);
    k_node<<<(n * 4 + 255) / 256, 256, 0, stream>>>(fsrc, attn_l, attn_r, ntype, el, er, n * 4);
    k_ee<<<1, 32, 0, stream>>>(W_e, edge_emb, attn_e, eet);
    k_escore<<<(ne + 255) / 256, 256, 0, stream>>>(src, dst, etype, el, er, eet, aBuf, menc, ne);
    k_eexp<<<(ne + 255) / 256, 256, 0, stream>>>(dst, menc, aBuf, den, ne);
    k_norm<<<(ne + 255) / 256, 256, 0, stream>>>(dst, den, aBuf, ne);
    k_agg<<<(ne + 1) / 2, 256, 0, stream>>>(src, dst, aBuf, fsrc, rst, ne);
}

// Round 3
// 692.553 us; speedup vs baseline: 1.2292x; 1.2292x over previous
//
#include <hip/hip_runtime.h>
#include <hip/hip_bf16.h>

#define N_IN   128
#define N_H    4
#define N_D    32
#define NEG_SLOPE 0.2f

// ---------- 1) feat_src = feat @ W_fc^T  (n,128)x(128,128)^T ----------
#define PR_ROWS 16
__global__ __launch_bounds__(256) void k_proj(const float* __restrict__ feat,
                                              const float* __restrict__ Wfc,
                                              float* __restrict__ fsrc, int n) {
    // W[c][k] stored at wt[c*128 + (k ^ ((c&7)<<2))] -> b128 reads conflict-free
    __shared__ float wt[128 * 128];
    __shared__ float fs[PR_ROWS * 128];
    const int t = threadIdx.x;
    for (int idx = t; idx < 128 * 128; idx += 256) {
        int cc = idx >> 7, kk = idx & 127;
        wt[cc * 128 + (kk ^ ((cc & 7) << 2))] = Wfc[idx];
    }
    const int c0 = t & 63;        // col
    const int rq = t >> 6;        // 0..3 row group
    const int sw = (c0 & 7) << 2; // same for c0+64
    const int nchunks = (n + PR_ROWS - 1) / PR_ROWS;
    for (int chunk = blockIdx.x; chunk < nchunks; chunk += gridDim.x) {
        const int base = chunk * PR_ROWS;
        __syncthreads();
        #pragma unroll
        for (int j = 0; j < PR_ROWS * 128 / 256; ++j) {
            int idx = t + j * 256;
            int r = idx >> 7, k = idx & 127;
            fs[idx] = (base + r < n) ? feat[(size_t)(base + r) * 128 + k] : 0.f;
        }
        __syncthreads();
        float acc[4][2];
        #pragma unroll
        for (int i = 0; i < 4; ++i) { acc[i][0] = 0.f; acc[i][1] = 0.f; }
        #pragma unroll 8
        for (int kq = 0; kq < 32; ++kq) {
            int k4 = kq * 4;
            float4 w0 = *(const float4*)&wt[c0 * 128 + (k4 ^ sw)];
            float4 w1 = *(const float4*)&wt[(c0 + 64) * 128 + (k4 ^ sw)];
            #pragma unroll
            for (int i = 0; i < 4; ++i) {
                float4 f = *(const float4*)&fs[(rq + 4 * i) * 128 + k4];
                acc[i][0] = fmaf(f.x, w0.x, acc[i][0]);
                acc[i][0] = fmaf(f.y, w0.y, acc[i][0]);
                acc[i][0] = fmaf(f.z, w0.z, acc[i][0]);
                acc[i][0] = fmaf(f.w, w0.w, acc[i][0]);
                acc[i][1] = fmaf(f.x, w1.x, acc[i][1]);
                acc[i][1] = fmaf(f.y, w1.y, acc[i][1]);
                acc[i][1] = fmaf(f.z, w1.z, acc[i][1]);
                acc[i][1] = fmaf(f.w, w1.w, acc[i][1]);
            }
        }
        #pragma unroll
        for (int i = 0; i < 4; ++i) {
            int r = base + rq + 4 * i;
            if (r < n) {
                fsrc[(size_t)r * 128 + c0]      = acc[i][0];
                fsrc[(size_t)r * 128 + c0 + 64] = acc[i][1];
            }
        }
    }
}

// ---------- 2) el/er per (node, head) ----------
__global__ void k_node(const float* __restrict__ fsrc, const float* __restrict__ attn_l,
                       const float* __restrict__ attn_r, const int* __restrict__ ntype,
                       float* __restrict__ el, float* __restrict__ er, int nh) {
    int t = blockIdx.x * blockDim.x + threadIdx.x;
    if (t >= nh) return;
    int nid = t >> 2, h = t & 3;
    int nt = ntype[nid];
    const float4* f4 = (const float4*)(fsrc + (size_t)nid * 128 + h * 32);
    const float4* l4 = (const float4*)(attn_l + ((size_t)nt * 4 + h) * 32);
    const float4* r4 = (const float4*)(attn_r + ((size_t)nt * 4 + h) * 32);
    float sl = 0.f, sr = 0.f;
    #pragma unroll
    for (int j = 0; j < 8; ++j) {
        float4 f = f4[j], l = l4[j], r = r4[j];
        sl += f.x * l.x + f.y * l.y + f.z * l.z + f.w * l.w;
        sr += f.x * r.x + f.y * r.y + f.z * r.z + f.w * r.w;
    }
    el[t] = sl;
    er[t] = sr;
}

// ---------- 3) ee table: only ET*H distinct values ----------
__global__ void k_ee(const float* __restrict__ W_e, const float* __restrict__ edge_emb,
                     const float* __restrict__ attn_e, float* __restrict__ eet) {
    int t = threadIdx.x;
    if (t >= 8 * 4) return;
    int et = t >> 2, h = t & 3;
    float ee = 0.f;
    for (int f = 0; f < 32; ++f) {
        float acc = 0.f;
        for (int g = 0; g < 32; ++g)
            acc += W_e[((size_t)h * 32 + f) * 32 + g] * edge_emb[et * 32 + g];
        ee += acc * attn_e[((size_t)et * 4 + h) * 32 + f];
    }
    eet[t] = ee * (float)et;
}

// ---------- 4) edge scores + leaky relu -> sBuf(=a out region); deg histogram ----------
__global__ void k_escore(const int* __restrict__ src, const int* __restrict__ dst,
                         const int* __restrict__ etype, const float* __restrict__ el,
                         const float* __restrict__ er, const float* __restrict__ eet,
                         float* __restrict__ sBuf, int* __restrict__ deg, int ne) {
    int e = blockIdx.x * blockDim.x + threadIdx.x;
    if (e >= ne) return;
    int s = src[e], d = dst[e], et = etype[e];
    float4 l = *(const float4*)(el + (size_t)s * 4);
    float4 r = *(const float4*)(er + (size_t)d * 4);
    float4 te = *(const float4*)(eet + (size_t)et * 4);
    float4 v;
    v.x = l.x + r.x + te.x;
    v.y = l.y + r.y + te.y;
    v.z = l.z + r.z + te.z;
    v.w = l.w + r.w + te.w;
    v.x = v.x > 0.f ? v.x : NEG_SLOPE * v.x;
    v.y = v.y > 0.f ? v.y : NEG_SLOPE * v.y;
    v.z = v.z > 0.f ? v.z : NEG_SLOPE * v.z;
    v.w = v.w > 0.f ? v.w : NEG_SLOPE * v.w;
    *(float4*)(sBuf + (size_t)e * 4) = v;
    atomicAdd(deg + d, 1);
}

// ---------- 5) exclusive scan of deg -> offs[n+1], cursor (single block) ----------
__global__ __launch_bounds__(1024) void k_scan(const int* __restrict__ deg,
                                               int* __restrict__ offs,
                                               int* __restrict__ cursor, int n) {
    __shared__ int part[1024];
    const int t = threadIdx.x;
    const int per = (n + 1023) / 1024;
    const int base = t * per;
    int s = 0;
    for (int i = 0; i < per; ++i) {
        int idx = base + i;
        if (idx < n) s += deg[idx];
    }
    part[t] = s;
    __syncthreads();
    for (int off = 1; off < 1024; off <<= 1) {
        int add = (t >= off) ? part[t - off] : 0;
        __syncthreads();
        part[t] += add;
        __syncthreads();
    }
    int run = part[t] - s;   // exclusive prefix for this thread's range
    for (int i = 0; i < per; ++i) {
        int idx = base + i;
        if (idx < n) {
            offs[idx] = run;
            cursor[idx] = run;
            run += deg[idx];
        }
    }
    if (t == 1023) offs[n] = part[1023];
}

// ---------- 6) scatter edge ids into CSR ----------
__global__ void k_scatter(const int* __restrict__ dst, int* __restrict__ cursor,
                          int* __restrict__ eidx, int ne) {
    int e = blockIdx.x * blockDim.x + threadIdx.x;
    if (e >= ne) return;
    int d = dst[e];
    int pos = atomicAdd(cursor + d, 1);
    eidx[pos] = e;
}

// ---------- 7) per-dst softmax + aggregate, no atomics ----------
// one block of 128 threads per dst node; thread j owns output column j (head j>>5)
__global__ __launch_bounds__(128) void k_aggfull(const int* __restrict__ offs,
                                                 const int* __restrict__ eidx,
                                                 const int* __restrict__ src,
                                                 const float* __restrict__ fsrc,
                                                 float* __restrict__ aBuf,   // in: scores, out: a
                                                 float* __restrict__ rst) {
    const int d = blockIdx.x;
    const int j = threadIdx.x;
    const int h = j >> 5;
    const int b = offs[d], e1 = offs[d + 1];
    // pass 1: max
    float m = -1e30f;
    for (int k = b; k < e1; ++k) {
        float s = aBuf[(size_t)eidx[k] * 4 + h];
        m = fmaxf(m, s);
    }
    // pass 2: denom
    float den = 0.f;
    for (int k = b; k < e1; ++k) {
        float s = aBuf[(size_t)eidx[k] * 4 + h];
        den += __expf(s - m);
    }
    float rden = (den > 0.f) ? 1.f / den : 0.f;
    // pass 3: normalize (write a) + aggregate
    float acc = 0.f;
    for (int k = b; k < e1; ++k) {
        int e = eidx[k];
        float s = aBuf[(size_t)e * 4 + h];
        float a = __expf(s - m) * rden;
        if ((j & 31) == 0) aBuf[(size_t)e * 4 + h] = a;
        int sn = src[e];
        acc = fmaf(a, fsrc[(size_t)sn * 128 + j], acc);
    }
    rst[(size_t)d * 128 + j] = acc;
}

extern "C" void kernel_launch(void* const* d_in, const int* in_sizes, int n_in,
                              void* d_out, int out_size, void* d_ws, size_t ws_size,
                              hipStream_t stream) {
    const float* feat     = (const float*)d_in[0];
    const float* W_fc     = (const float*)d_in[1];
    const float* W_e      = (const float*)d_in[2];
    const float* edge_emb = (const float*)d_in[3];
    const float* attn_l   = (const float*)d_in[4];
    const float* attn_r   = (const float*)d_in[5];
    const float* attn_e   = (const float*)d_in[6];
    const int* src   = (const int*)d_in[7];
    const int* dst   = (const int*)d_in[8];
    const int* etype = (const int*)d_in[9];
    const int* ntype = (const int*)d_in[10];
    const int n  = in_sizes[0] / N_IN;
    const int ne = in_sizes[7];

    // workspace layout
    float* ws   = (float*)d_ws;
    float* fsrc = ws;                                 // n*128 f
    float* el   = fsrc + (size_t)n * 128;             // n*4 f
    float* er   = el + (size_t)n * 4;                 // n*4 f
    float* eet  = er + (size_t)n * 4;                 // 32 f
    int* deg    = (int*)(eet + 32);                   // n i
    int* offs   = deg + n;                            // n+1 i
    int* cursor = offs + n + 1;                       // n i
    int* eidx   = cursor + n;                         // ne i

    float* rst  = (float*)d_out;                      // n*128
    float* aBuf = rst + (size_t)n * 128;              // ne*4: scores then final a

    hipMemsetAsync(deg, 0, (size_t)n * sizeof(int), stream);

    k_proj<<<512, 256, 0, stream>>>(feat, W_fc, fsrc, n);
    k_node<<<(n * 4 + 255) / 256, 256, 0, stream>>>(fsrc, attn_l, attn_r, ntype, el, er, n * 4);
    k_ee<<<1, 32, 0, stream>>>(W_e, edge_emb, attn_e, eet);
    k_escore<<<(ne + 255) / 256, 256, 0, stream>>>(src, dst, etype, el, er, eet, aBuf, deg, ne);
    k_scan<<<1, 1024, 0, stream>>>(deg, offs, cursor, n);
    k_scatter<<<(ne + 255) / 256, 256, 0, stream>>>(dst, cursor, eidx, ne);
    k_aggfull<<<n, 128, 0, stream>>>(offs, eidx, src, fsrc, aBuf, rst);
}

// Round 4
// 489.830 us; speedup vs baseline: 1.7379x; 1.4139x over previous
//
#include <hip/hip_runtime.h>
#include <hip/hip_bf16.h>

#define N_IN   128
#define N_H    4
#define N_D    32
#define NEG_SLOPE 0.2f

// ---------- 1) feat_src = feat @ W_fc^T  (n,128)x(128,128)^T ----------
// writes fp32 fsrc (for el/er) and bf16 fsrcb (for the aggregation gather)
#define PR_ROWS 16
__global__ __launch_bounds__(256) void k_proj(const float* __restrict__ feat,
                                              const float* __restrict__ Wfc,
                                              float* __restrict__ fsrc,
                                              __hip_bfloat16* __restrict__ fsrcb, int n) {
    // W[c][k] stored at wt[c*128 + (k ^ ((c&7)<<2))] -> b128 reads conflict-free
    __shared__ float wt[128 * 128];
    __shared__ float fs[PR_ROWS * 128];
    const int t = threadIdx.x;
    for (int idx = t; idx < 128 * 128; idx += 256) {
        int cc = idx >> 7, kk = idx & 127;
        wt[cc * 128 + (kk ^ ((cc & 7) << 2))] = Wfc[idx];
    }
    const int c0 = t & 63;        // col
    const int rq = t >> 6;        // 0..3 row group
    const int sw = (c0 & 7) << 2; // same for c0+64
    const int nchunks = (n + PR_ROWS - 1) / PR_ROWS;
    for (int chunk = blockIdx.x; chunk < nchunks; chunk += gridDim.x) {
        const int base = chunk * PR_ROWS;
        __syncthreads();
        #pragma unroll
        for (int j = 0; j < PR_ROWS * 128 / 256; ++j) {
            int idx = t + j * 256;
            int r = idx >> 7, k = idx & 127;
            fs[idx] = (base + r < n) ? feat[(size_t)(base + r) * 128 + k] : 0.f;
        }
        __syncthreads();
        float acc[4][2];
        #pragma unroll
        for (int i = 0; i < 4; ++i) { acc[i][0] = 0.f; acc[i][1] = 0.f; }
        #pragma unroll 8
        for (int kq = 0; kq < 32; ++kq) {
            int k4 = kq * 4;
            float4 w0 = *(const float4*)&wt[c0 * 128 + (k4 ^ sw)];
            float4 w1 = *(const float4*)&wt[(c0 + 64) * 128 + (k4 ^ sw)];
            #pragma unroll
            for (int i = 0; i < 4; ++i) {
                float4 f = *(const float4*)&fs[(rq + 4 * i) * 128 + k4];
                acc[i][0] = fmaf(f.x, w0.x, acc[i][0]);
                acc[i][0] = fmaf(f.y, w0.y, acc[i][0]);
                acc[i][0] = fmaf(f.z, w0.z, acc[i][0]);
                acc[i][0] = fmaf(f.w, w0.w, acc[i][0]);
                acc[i][1] = fmaf(f.x, w1.x, acc[i][1]);
                acc[i][1] = fmaf(f.y, w1.y, acc[i][1]);
                acc[i][1] = fmaf(f.z, w1.z, acc[i][1]);
                acc[i][1] = fmaf(f.w, w1.w, acc[i][1]);
            }
        }
        #pragma unroll
        for (int i = 0; i < 4; ++i) {
            int r = base + rq + 4 * i;
            if (r < n) {
                fsrc[(size_t)r * 128 + c0]      = acc[i][0];
                fsrc[(size_t)r * 128 + c0 + 64] = acc[i][1];
                fsrcb[(size_t)r * 128 + c0]      = __float2bfloat16(acc[i][0]);
                fsrcb[(size_t)r * 128 + c0 + 64] = __float2bfloat16(acc[i][1]);
            }
        }
    }
}

// ---------- 2) el/er per (node, head) ----------
__global__ void k_node(const float* __restrict__ fsrc, const float* __restrict__ attn_l,
                       const float* __restrict__ attn_r, const int* __restrict__ ntype,
                       float* __restrict__ el, float* __restrict__ er, int nh) {
    int t = blockIdx.x * blockDim.x + threadIdx.x;
    if (t >= nh) return;
    int nid = t >> 2, h = t & 3;
    int nt = ntype[nid];
    const float4* f4 = (const float4*)(fsrc + (size_t)nid * 128 + h * 32);
    const float4* l4 = (const float4*)(attn_l + ((size_t)nt * 4 + h) * 32);
    const float4* r4 = (const float4*)(attn_r + ((size_t)nt * 4 + h) * 32);
    float sl = 0.f, sr = 0.f;
    #pragma unroll
    for (int j = 0; j < 8; ++j) {
        float4 f = f4[j], l = l4[j], r = r4[j];
        sl += f.x * l.x + f.y * l.y + f.z * l.z + f.w * l.w;
        sr += f.x * r.x + f.y * r.y + f.z * r.z + f.w * r.w;
    }
    el[t] = sl;
    er[t] = sr;
}

// ---------- 3) ee table: only ET*H distinct values ----------
__global__ void k_ee(const float* __restrict__ W_e, const float* __restrict__ edge_emb,
                     const float* __restrict__ attn_e, float* __restrict__ eet) {
    int t = threadIdx.x;
    if (t >= 8 * 4) return;
    int et = t >> 2, h = t & 3;
    float ee = 0.f;
    for (int f = 0; f < 32; ++f) {
        float acc = 0.f;
        for (int g = 0; g < 32; ++g)
            acc += W_e[((size_t)h * 32 + f) * 32 + g] * edge_emb[et * 32 + g];
        ee += acc * attn_e[((size_t)et * 4 + h) * 32 + f];
    }
    eet[t] = ee * (float)et;
}

// ---------- 4) edge scores + leaky relu -> aBuf; deg histogram ----------
__global__ void k_escore(const int* __restrict__ src, const int* __restrict__ dst,
                         const int* __restrict__ etype, const float* __restrict__ el,
                         const float* __restrict__ er, const float* __restrict__ eet,
                         float* __restrict__ sBuf, int* __restrict__ deg, int ne) {
    int e = blockIdx.x * blockDim.x + threadIdx.x;
    if (e >= ne) return;
    int s = src[e], d = dst[e], et = etype[e];
    float4 l = *(const float4*)(el + (size_t)s * 4);
    float4 r = *(const float4*)(er + (size_t)d * 4);
    float4 te = *(const float4*)(eet + (size_t)et * 4);
    float4 v;
    v.x = l.x + r.x + te.x;
    v.y = l.y + r.y + te.y;
    v.z = l.z + r.z + te.z;
    v.w = l.w + r.w + te.w;
    v.x = v.x > 0.f ? v.x : NEG_SLOPE * v.x;
    v.y = v.y > 0.f ? v.y : NEG_SLOPE * v.y;
    v.z = v.z > 0.f ? v.z : NEG_SLOPE * v.z;
    v.w = v.w > 0.f ? v.w : NEG_SLOPE * v.w;
    *(float4*)(sBuf + (size_t)e * 4) = v;
    atomicAdd(deg + d, 1);
}

// ---------- 5) exclusive scan of deg -> offs[n+1], cursor (single block) ----------
__global__ __launch_bounds__(1024) void k_scan(const int* __restrict__ deg,
                                               int* __restrict__ offs,
                                               int* __restrict__ cursor, int n) {
    __shared__ int part[1024];
    const int t = threadIdx.x;
    const int per = (n + 1023) / 1024;
    const int base = t * per;
    int s = 0;
    for (int i = 0; i < per; ++i) {
        int idx = base + i;
        if (idx < n) s += deg[idx];
    }
    part[t] = s;
    __syncthreads();
    for (int off = 1; off < 1024; off <<= 1) {
        int add = (t >= off) ? part[t - off] : 0;
        __syncthreads();
        part[t] += add;
        __syncthreads();
    }
    int run = part[t] - s;   // exclusive prefix for this thread's range
    for (int i = 0; i < per; ++i) {
        int idx = base + i;
        if (idx < n) {
            offs[idx] = run;
            cursor[idx] = run;
            run += deg[idx];
        }
    }
    if (t == 1023) offs[n] = part[1023];
}

// ---------- 6) scatter edge ids into CSR ----------
__global__ void k_scatter(const int* __restrict__ dst, int* __restrict__ cursor,
                          int* __restrict__ eidx, int ne) {
    int e = blockIdx.x * blockDim.x + threadIdx.x;
    if (e >= ne) return;
    int d = dst[e];
    int pos = atomicAdd(cursor + d, 1);
    eidx[pos] = e;
}

// ---------- 7) per-dst softmax + aggregate: LDS-staged, single gather pass ----------
// 128 threads per dst node; thread j owns output column j (head h=j>>5)
#define CHUNK 128
__global__ __launch_bounds__(128) void k_aggfull(const int* __restrict__ offs,
                                                 const int* __restrict__ eidx,
                                                 const int* __restrict__ src,
                                                 const __hip_bfloat16* __restrict__ fsrcb,
                                                 float* __restrict__ aBuf,   // in: scores, out: a
                                                 float* __restrict__ rst) {
    __shared__ int   s_src[CHUNK];
    __shared__ float s_sc[4][CHUNK];   // [head][edge] -> conflict-free staging writes
    __shared__ float s_m[4], s_rd[4];
    const int d = blockIdx.x;
    const int j = threadIdx.x;
    const int h = j >> 5;
    const int b = offs[d], e1 = offs[d + 1];
    const int deg = e1 - b;

    float m = -1e30f, den = 0.f, acc = 0.f;
    for (int c0 = 0; c0 < deg; c0 += CHUNK) {
        const int cn = min(CHUNK, deg - c0);
        if (j < cn) {
            int e = eidx[b + c0 + j];
            s_src[j] = src[e];
            float4 sc = *(const float4*)(aBuf + (size_t)e * 4);
            s_sc[0][j] = sc.x; s_sc[1][j] = sc.y; s_sc[2][j] = sc.z; s_sc[3][j] = sc.w;
        }
        __syncthreads();
        // chunk max (LDS broadcast reads)
        float mc = m;
        for (int k = 0; k < cn; ++k) mc = fmaxf(mc, s_sc[h][k]);
        float scale = __expf(m - mc);        // first chunk: exp(-inf)=0, den/acc are 0 anyway
        den *= scale; acc *= scale; m = mc;
        // single gather pass: addresses come from LDS -> 1-deep chains, full MLP
        for (int k = 0; k < cn; ++k) {
            float p = __expf(s_sc[h][k] - m);
            den += p;
            acc = fmaf(p, __bfloat162float(fsrcb[(size_t)s_src[k] * 128 + j]), acc);
        }
        __syncthreads();   // protect s_src/s_sc before next chunk's staging
    }
    float rden = (den > 0.f) ? 1.f / den : 0.f;
    rst[(size_t)d * 128 + j] = acc * rden;

    // publish per-head m, rden for the a-write pass
    if ((j & 31) == 0) { s_m[h] = m; s_rd[h] = rden; }
    __syncthreads();

    if (deg <= CHUNK) {
        // scores still in LDS from the (single) chunk
        if (j < deg) {
            int e = eidx[b + j];
            float4 a;
            a.x = __expf(s_sc[0][j] - s_m[0]) * s_rd[0];
            a.y = __expf(s_sc[1][j] - s_m[1]) * s_rd[1];
            a.z = __expf(s_sc[2][j] - s_m[2]) * s_rd[2];
            a.w = __expf(s_sc[3][j] - s_m[3]) * s_rd[3];
            *(float4*)(aBuf + (size_t)e * 4) = a;
        }
    } else {
        for (int k0 = 0; k0 < deg; k0 += CHUNK) {
            int k = k0 + j;
            if (k < deg) {
                int e = eidx[b + k];
                float4 sc = *(const float4*)(aBuf + (size_t)e * 4);
                float4 a;
                a.x = __expf(sc.x - s_m[0]) * s_rd[0];
                a.y = __expf(sc.y - s_m[1]) * s_rd[1];
                a.z = __expf(sc.z - s_m[2]) * s_rd[2];
                a.w = __expf(sc.w - s_m[3]) * s_rd[3];
                *(float4*)(aBuf + (size_t)e * 4) = a;
            }
        }
    }
}

extern "C" void kernel_launch(void* const* d_in, const int* in_sizes, int n_in,
                              void* d_out, int out_size, void* d_ws, size_t ws_size,
                              hipStream_t stream) {
    const float* feat     = (const float*)d_in[0];
    const float* W_fc     = (const float*)d_in[1];
    const float* W_e      = (const float*)d_in[2];
    const float* edge_emb = (const float*)d_in[3];
    const float* attn_l   = (const float*)d_in[4];
    const float* attn_r   = (const float*)d_in[5];
    const float* attn_e   = (const float*)d_in[6];
    const int* src   = (const int*)d_in[7];
    const int* dst   = (const int*)d_in[8];
    const int* etype = (const int*)d_in[9];
    const int* ntype = (const int*)d_in[10];
    const int n  = in_sizes[0] / N_IN;
    const int ne = in_sizes[7];

    // workspace layout
    float* ws   = (float*)d_ws;
    float* fsrc = ws;                                 // n*128 f
    float* el   = fsrc + (size_t)n * 128;             // n*4 f
    float* er   = el + (size_t)n * 4;                 // n*4 f
    float* eet  = er + (size_t)n * 4;                 // 32 f
    int* deg    = (int*)(eet + 32);                   // n i
    int* offs   = deg + n;                            // n+1 i
    int* cursor = offs + n + 1;                       // n i
    int* eidx   = cursor + n;                         // ne i
    __hip_bfloat16* fsrcb = (__hip_bfloat16*)(eidx + ne); // n*128 bf16

    float* rst  = (float*)d_out;                      // n*128
    float* aBuf = rst + (size_t)n * 128;              // ne*4: scores then final a

    hipMemsetAsync(deg, 0, (size_t)n * sizeof(int), stream);

    k_proj<<<512, 256, 0, stream>>>(feat, W_fc, fsrc, fsrcb, n);
    k_node<<<(n * 4 + 255) / 256, 256, 0, stream>>>(fsrc, attn_l, attn_r, ntype, el, er, n * 4);
    k_ee<<<1, 32, 0, stream>>>(W_e, edge_emb, attn_e, eet);
    k_escore<<<(ne + 255) / 256, 256, 0, stream>>>(src, dst, etype, el, er, eet, aBuf, deg, ne);
    k_scan<<<1, 1024, 0, stream>>>(deg, offs, cursor, n);
    k_scatter<<<(ne + 255) / 256, 256, 0, stream>>>(dst, cursor, eidx, ne);
    k_aggfull<<<n, 128, 0, stream>>>(offs, eidx, src, fsrcb, aBuf, rst);
}

// Round 6
// 376.562 us; speedup vs baseline: 2.2607x; 1.3008x over previous
//
#include <hip/hip_runtime.h>
#include <hip/hip_bf16.h>

#define N_IN   128
#define N_H    4
#define N_D    32
#define NEG_SLOPE 0.2f

// ---------- 1) feat_src = feat @ W_fc^T  (n,128)x(128,128)^T ----------
// writes fp32 fsrc (for el/er) and bf16 fsrcb (for the aggregation gather)
#define PR_ROWS 16
__global__ __launch_bounds__(256) void k_proj(const float* __restrict__ feat,
                                              const float* __restrict__ Wfc,
                                              float* __restrict__ fsrc,
                                              __hip_bfloat16* __restrict__ fsrcb, int n) {
    // W[c][k] stored at wt[c*128 + (k ^ ((c&7)<<2))] -> b128 reads conflict-free
    __shared__ float wt[128 * 128];
    __shared__ float fs[PR_ROWS * 128];
    const int t = threadIdx.x;
    for (int idx = t; idx < 128 * 128; idx += 256) {
        int cc = idx >> 7, kk = idx & 127;
        wt[cc * 128 + (kk ^ ((cc & 7) << 2))] = Wfc[idx];
    }
    const int c0 = t & 63;        // col
    const int rq = t >> 6;        // 0..3 row group
    const int sw = (c0 & 7) << 2; // same for c0+64
    const int nchunks = (n + PR_ROWS - 1) / PR_ROWS;
    for (int chunk = blockIdx.x; chunk < nchunks; chunk += gridDim.x) {
        const int base = chunk * PR_ROWS;
        __syncthreads();
        #pragma unroll
        for (int j = 0; j < PR_ROWS * 128 / 256; ++j) {
            int idx = t + j * 256;
            int r = idx >> 7, k = idx & 127;
            fs[idx] = (base + r < n) ? feat[(size_t)(base + r) * 128 + k] : 0.f;
        }
        __syncthreads();
        float acc[4][2];
        #pragma unroll
        for (int i = 0; i < 4; ++i) { acc[i][0] = 0.f; acc[i][1] = 0.f; }
        #pragma unroll 8
        for (int kq = 0; kq < 32; ++kq) {
            int k4 = kq * 4;
            float4 w0 = *(const float4*)&wt[c0 * 128 + (k4 ^ sw)];
            float4 w1 = *(const float4*)&wt[(c0 + 64) * 128 + (k4 ^ sw)];
            #pragma unroll
            for (int i = 0; i < 4; ++i) {
                float4 f = *(const float4*)&fs[(rq + 4 * i) * 128 + k4];
                acc[i][0] = fmaf(f.x, w0.x, acc[i][0]);
                acc[i][0] = fmaf(f.y, w0.y, acc[i][0]);
                acc[i][0] = fmaf(f.z, w0.z, acc[i][0]);
                acc[i][0] = fmaf(f.w, w0.w, acc[i][0]);
                acc[i][1] = fmaf(f.x, w1.x, acc[i][1]);
                acc[i][1] = fmaf(f.y, w1.y, acc[i][1]);
                acc[i][1] = fmaf(f.z, w1.z, acc[i][1]);
                acc[i][1] = fmaf(f.w, w1.w, acc[i][1]);
            }
        }
        #pragma unroll
        for (int i = 0; i < 4; ++i) {
            int r = base + rq + 4 * i;
            if (r < n) {
                fsrc[(size_t)r * 128 + c0]      = acc[i][0];
                fsrc[(size_t)r * 128 + c0 + 64] = acc[i][1];
                fsrcb[(size_t)r * 128 + c0]      = __float2bfloat16(acc[i][0]);
                fsrcb[(size_t)r * 128 + c0 + 64] = __float2bfloat16(acc[i][1]);
            }
        }
    }
}

// ---------- 2) el/er per (node, head) ----------
__global__ void k_node(const float* __restrict__ fsrc, const float* __restrict__ attn_l,
                       const float* __restrict__ attn_r, const int* __restrict__ ntype,
                       float* __restrict__ el, float* __restrict__ er, int nh) {
    int t = blockIdx.x * blockDim.x + threadIdx.x;
    if (t >= nh) return;
    int nid = t >> 2, h = t & 3;
    int nt = ntype[nid];
    const float4* f4 = (const float4*)(fsrc + (size_t)nid * 128 + h * 32);
    const float4* l4 = (const float4*)(attn_l + ((size_t)nt * 4 + h) * 32);
    const float4* r4 = (const float4*)(attn_r + ((size_t)nt * 4 + h) * 32);
    float sl = 0.f, sr = 0.f;
    #pragma unroll
    for (int j = 0; j < 8; ++j) {
        float4 f = f4[j], l = l4[j], r = r4[j];
        sl += f.x * l.x + f.y * l.y + f.z * l.z + f.w * l.w;
        sr += f.x * r.x + f.y * r.y + f.z * r.z + f.w * r.w;
    }
    el[t] = sl;
    er[t] = sr;
}

// ---------- 3) ee table: only ET*H distinct values ----------
__global__ void k_ee(const float* __restrict__ W_e, const float* __restrict__ edge_emb,
                     const float* __restrict__ attn_e, float* __restrict__ eet) {
    int t = threadIdx.x;
    if (t >= 8 * 4) return;
    int et = t >> 2, h = t & 3;
    float ee = 0.f;
    for (int f = 0; f < 32; ++f) {
        float acc = 0.f;
        for (int g = 0; g < 32; ++g)
            acc += W_e[((size_t)h * 32 + f) * 32 + g] * edge_emb[et * 32 + g];
        ee += acc * attn_e[((size_t)et * 4 + h) * 32 + f];
    }
    eet[t] = ee * (float)et;
}

// ---------- 4) edge scores + leaky relu -> aBuf; deg histogram ----------
__global__ void k_escore(const int* __restrict__ src, const int* __restrict__ dst,
                         const int* __restrict__ etype, const float* __restrict__ el,
                         const float* __restrict__ er, const float* __restrict__ eet,
                         float* __restrict__ sBuf, int* __restrict__ deg, int ne) {
    int e = blockIdx.x * blockDim.x + threadIdx.x;
    if (e >= ne) return;
    int s = src[e], d = dst[e], et = etype[e];
    float4 l = *(const float4*)(el + (size_t)s * 4);
    float4 r = *(const float4*)(er + (size_t)d * 4);
    float4 te = *(const float4*)(eet + (size_t)et * 4);
    float4 v;
    v.x = l.x + r.x + te.x;
    v.y = l.y + r.y + te.y;
    v.z = l.z + r.z + te.z;
    v.w = l.w + r.w + te.w;
    v.x = v.x > 0.f ? v.x : NEG_SLOPE * v.x;
    v.y = v.y > 0.f ? v.y : NEG_SLOPE * v.y;
    v.z = v.z > 0.f ? v.z : NEG_SLOPE * v.z;
    v.w = v.w > 0.f ? v.w : NEG_SLOPE * v.w;
    *(float4*)(sBuf + (size_t)e * 4) = v;
    atomicAdd(deg + d, 1);
}

// ---------- 5) hierarchical exclusive scan: deg -> offs[n+1], cursor ----------
#define SC_ELEMS 1024   // elements per scan tile (256 threads x 4)
__global__ __launch_bounds__(256) void k_scan_sum(const int* __restrict__ deg,
                                                  int* __restrict__ bsum, int n) {
    __shared__ int red[256];
    const int t = threadIdx.x;
    const int base = blockIdx.x * SC_ELEMS;
    int s = 0;
    #pragma unroll
    for (int i = 0; i < 4; ++i) {
        int idx = base + t * 4 + i;
        if (idx < n) s += deg[idx];
    }
    red[t] = s;
    __syncthreads();
    for (int off = 128; off > 0; off >>= 1) {
        if (t < off) red[t] += red[t + off];
        __syncthreads();
    }
    if (t == 0) bsum[blockIdx.x] = red[0];
}

__global__ __launch_bounds__(1024) void k_scan_mid(int* __restrict__ bsum, int nb) {
    __shared__ int sh[1024];
    const int t = threadIdx.x;
    int v = (t < nb) ? bsum[t] : 0;
    sh[t] = v;
    __syncthreads();
    for (int off = 1; off < 1024; off <<= 1) {
        int add = (t >= off) ? sh[t - off] : 0;
        __syncthreads();
        sh[t] += add;
        __syncthreads();
    }
    if (t < nb) bsum[t] = sh[t] - v;   // exclusive
}

__global__ __launch_bounds__(256) void k_scan_out(const int* __restrict__ deg,
                                                  const int* __restrict__ bsum,
                                                  int* __restrict__ offs,
                                                  int* __restrict__ cursor, int n) {
    __shared__ int sh[256];
    const int t = threadIdx.x;
    const int base = blockIdx.x * SC_ELEMS + t * 4;
    int v[4], s = 0;
    #pragma unroll
    for (int i = 0; i < 4; ++i) {
        int idx = base + i;
        v[i] = (idx < n) ? deg[idx] : 0;
        s += v[i];
    }
    sh[t] = s;
    __syncthreads();
    const int mine = s;
    for (int off = 1; off < 256; off <<= 1) {
        int add = (t >= off) ? sh[t - off] : 0;
        __syncthreads();
        sh[t] += add;
        __syncthreads();
    }
    int run = bsum[blockIdx.x] + sh[t] - mine;
    #pragma unroll
    for (int i = 0; i < 4; ++i) {
        int idx = base + i;
        if (idx < n) { offs[idx] = run; cursor[idx] = run; run += v[i]; }
    }
    // last thread of last block ends with run == total (pad elems add 0)
    if (blockIdx.x == gridDim.x - 1 && t == 255) offs[n] = run;
}

// ---------- 6) scatter edge ids into CSR ----------
__global__ void k_scatter(const int* __restrict__ dst, int* __restrict__ cursor,
                          int* __restrict__ eidx, int ne) {
    int e = blockIdx.x * blockDim.x + threadIdx.x;
    if (e >= ne) return;
    int d = dst[e];
    int pos = atomicAdd(cursor + d, 1);
    eidx[pos] = e;
}

// ---------- 7) per-dst softmax + aggregate: LDS-staged, single gather pass ----------
// 128 threads per dst node; thread j owns output column j (head h=j>>5)
#define CHUNK 128
__global__ __launch_bounds__(128) void k_aggfull(const int* __restrict__ offs,
                                                 const int* __restrict__ eidx,
                                                 const int* __restrict__ src,
                                                 const __hip_bfloat16* __restrict__ fsrcb,
                                                 float* __restrict__ aBuf,   // in: scores, out: a
                                                 float* __restrict__ rst) {
    __shared__ int   s_src[CHUNK];
    __shared__ float s_sc[4][CHUNK];   // [head][edge] -> conflict-free staging writes
    __shared__ float s_m[4], s_rd[4];
    const int d = blockIdx.x;
    const int j = threadIdx.x;
    const int h = j >> 5;
    const int b = offs[d], e1 = offs[d + 1];
    const int deg = e1 - b;

    float m = -1e30f, den = 0.f, acc = 0.f;
    for (int c0 = 0; c0 < deg; c0 += CHUNK) {
        const int cn = min(CHUNK, deg - c0);
        if (j < cn) {
            int e = eidx[b + c0 + j];
            s_src[j] = src[e];
            float4 sc = *(const float4*)(aBuf + (size_t)e * 4);
            s_sc[0][j] = sc.x; s_sc[1][j] = sc.y; s_sc[2][j] = sc.z; s_sc[3][j] = sc.w;
        }
        __syncthreads();
        // chunk max (LDS broadcast reads)
        float mc = m;
        for (int k = 0; k < cn; ++k) mc = fmaxf(mc, s_sc[h][k]);
        float scale = __expf(m - mc);        // first chunk: exp(-inf)=0, den/acc are 0 anyway
        den *= scale; acc *= scale; m = mc;
        // single gather pass: addresses come from LDS -> 1-deep chains, full MLP
        for (int k = 0; k < cn; ++k) {
            float p = __expf(s_sc[h][k] - m);
            den += p;
            acc = fmaf(p, __bfloat162float(fsrcb[(size_t)s_src[k] * 128 + j]), acc);
        }
        __syncthreads();   // protect s_src/s_sc before next chunk's staging
    }
    float rden = (den > 0.f) ? 1.f / den : 0.f;
    rst[(size_t)d * 128 + j] = acc * rden;

    // publish per-head m, rden for the a-write pass
    if ((j & 31) == 0) { s_m[h] = m; s_rd[h] = rden; }
    __syncthreads();

    if (deg <= CHUNK) {
        // scores still in LDS from the (single) chunk
        if (j < deg) {
            int e = eidx[b + j];
            float4 a;
            a.x = __expf(s_sc[0][j] - s_m[0]) * s_rd[0];
            a.y = __expf(s_sc[1][j] - s_m[1]) * s_rd[1];
            a.z = __expf(s_sc[2][j] - s_m[2]) * s_rd[2];
            a.w = __expf(s_sc[3][j] - s_m[3]) * s_rd[3];
            *(float4*)(aBuf + (size_t)e * 4) = a;
        }
    } else {
        for (int k0 = 0; k0 < deg; k0 += CHUNK) {
            int k = k0 + j;
            if (k < deg) {
                int e = eidx[b + k];
                float4 sc = *(const float4*)(aBuf + (size_t)e * 4);
                float4 a;
                a.x = __expf(sc.x - s_m[0]) * s_rd[0];
                a.y = __expf(sc.y - s_m[1]) * s_rd[1];
                a.z = __expf(sc.z - s_m[2]) * s_rd[2];
                a.w = __expf(sc.w - s_m[3]) * s_rd[3];
                *(float4*)(aBuf + (size_t)e * 4) = a;
            }
        }
    }
}

extern "C" void kernel_launch(void* const* d_in, const int* in_sizes, int n_in,
                              void* d_out, int out_size, void* d_ws, size_t ws_size,
                              hipStream_t stream) {
    const float* feat     = (const float*)d_in[0];
    const float* W_fc     = (const float*)d_in[1];
    const float* W_e      = (const float*)d_in[2];
    const float* edge_emb = (const float*)d_in[3];
    const float* attn_l   = (const float*)d_in[4];
    const float* attn_r   = (const float*)d_in[5];
    const float* attn_e   = (const float*)d_in[6];
    const int* src   = (const int*)d_in[7];
    const int* dst   = (const int*)d_in[8];
    const int* etype = (const int*)d_in[9];
    const int* ntype = (const int*)d_in[10];
    const int n  = in_sizes[0] / N_IN;
    const int ne = in_sizes[7];

    // workspace layout
    float* ws   = (float*)d_ws;
    float* fsrc = ws;                                 // n*128 f
    float* el   = fsrc + (size_t)n * 128;             // n*4 f
    float* er   = el + (size_t)n * 4;                 // n*4 f
    float* eet  = er + (size_t)n * 4;                 // 32 f
    int* deg    = (int*)(eet + 32);                   // n i
    int* offs   = deg + n;                            // n+1 i
    int* cursor = offs + n + 1;                       // n i
    int* eidx   = cursor + n;                         // ne i
    __hip_bfloat16* fsrcb = (__hip_bfloat16*)(eidx + ne); // n*128 bf16
    int* bsum   = (int*)(fsrcb + (size_t)n * 128);    // <=1024 i

    float* rst  = (float*)d_out;                      // n*128
    float* aBuf = rst + (size_t)n * 128;              // ne*4: scores then final a

    const int nb = (n + SC_ELEMS - 1) / SC_ELEMS;

    hipMemsetAsync(deg, 0, (size_t)n * sizeof(int), stream);

    k_proj<<<512, 256, 0, stream>>>(feat, W_fc, fsrc, fsrcb, n);
    k_node<<<(n * 4 + 255) / 256, 256, 0, stream>>>(fsrc, attn_l, attn_r, ntype, el, er, n * 4);
    k_ee<<<1, 32, 0, stream>>>(W_e, edge_emb, attn_e, eet);
    k_escore<<<(ne + 255) / 256, 256, 0, stream>>>(src, dst, etype, el, er, eet, aBuf, deg, ne);
    k_scan_sum<<<nb, 256, 0, stream>>>(deg, bsum, n);
    k_scan_mid<<<1, 1024, 0, stream>>>(bsum, nb);
    k_scan_out<<<nb, 256, 0, stream>>>(deg, bsum, offs, cursor, n);
    k_scatter<<<(ne + 255) / 256, 256, 0, stream>>>(dst, cursor, eidx, ne);
    k_aggfull<<<n, 128, 0, stream>>>(offs, eidx, src, fsrcb, aBuf, rst);
}

// Round 7
// 333.090 us; speedup vs baseline: 2.5558x; 1.1305x over previous
//
#include <hip/hip_runtime.h>
#include <hip/hip_bf16.h>

#define N_IN   128
#define N_H    4
#define N_D    32
#define NEG_SLOPE 0.2f

// ---------- 1) k_proj: fsrcb(bf16) = feat @ W_fc^T, fused el/er epilogue ----------
#define PR_ROWS 16
__global__ __launch_bounds__(256) void k_proj(const float* __restrict__ feat,
                                              const float* __restrict__ Wfc,
                                              __hip_bfloat16* __restrict__ fsrcb,
                                              const float* __restrict__ attn_l,
                                              const float* __restrict__ attn_r,
                                              const int* __restrict__ ntype,
                                              float* __restrict__ el,
                                              float* __restrict__ er, int n) {
    // W[c][k] stored at wt[c*128 + (k ^ ((c&7)<<2))] -> b128 reads swizzled
    __shared__ float wt[128 * 128];
    __shared__ float fs[PR_ROWS * 128];
    const int t = threadIdx.x;
    for (int idx = t; idx < 128 * 128; idx += 256) {
        int cc = idx >> 7, kk = idx & 127;
        wt[cc * 128 + (kk ^ ((cc & 7) << 2))] = Wfc[idx];
    }
    const int c0 = t & 63;        // col
    const int rq = t >> 6;        // 0..3 row group (== wave id)
    const int sw = (c0 & 7) << 2; // same for c0+64
    const int dd = c0 & 31;       // dim within head
    const int ha = c0 >> 5;       // head 0/1 (col c0), head ha+2 for col c0+64
    const int nchunks = (n + PR_ROWS - 1) / PR_ROWS;
    for (int chunk = blockIdx.x; chunk < nchunks; chunk += gridDim.x) {
        const int base = chunk * PR_ROWS;
        __syncthreads();
        #pragma unroll
        for (int j = 0; j < PR_ROWS * 128 / 256; ++j) {
            int idx = t + j * 256;
            int r = idx >> 7, k = idx & 127;
            fs[idx] = (base + r < n) ? feat[(size_t)(base + r) * 128 + k] : 0.f;
        }
        __syncthreads();
        float acc[4][2];
        #pragma unroll
        for (int i = 0; i < 4; ++i) { acc[i][0] = 0.f; acc[i][1] = 0.f; }
        #pragma unroll 8
        for (int kq = 0; kq < 32; ++kq) {
            int k4 = kq * 4;
            float4 w0 = *(const float4*)&wt[c0 * 128 + (k4 ^ sw)];
            float4 w1 = *(const float4*)&wt[(c0 + 64) * 128 + (k4 ^ sw)];
            #pragma unroll
            for (int i = 0; i < 4; ++i) {
                float4 f = *(const float4*)&fs[(rq + 4 * i) * 128 + k4];
                acc[i][0] = fmaf(f.x, w0.x, acc[i][0]);
                acc[i][0] = fmaf(f.y, w0.y, acc[i][0]);
                acc[i][0] = fmaf(f.z, w0.z, acc[i][0]);
                acc[i][0] = fmaf(f.w, w0.w, acc[i][0]);
                acc[i][1] = fmaf(f.x, w1.x, acc[i][1]);
                acc[i][1] = fmaf(f.y, w1.y, acc[i][1]);
                acc[i][1] = fmaf(f.z, w1.z, acc[i][1]);
                acc[i][1] = fmaf(f.w, w1.w, acc[i][1]);
            }
        }
        #pragma unroll
        for (int i = 0; i < 4; ++i) {
            int r = base + rq + 4 * i;
            if (r < n) {
                fsrcb[(size_t)r * 128 + c0]      = __float2bfloat16(acc[i][0]);
                fsrcb[(size_t)r * 128 + c0 + 64] = __float2bfloat16(acc[i][1]);
                // fused el/er: dot(acc, attn) reduced over the 32-lane head group
                int nt = ntype[r];
                float la = attn_l[((size_t)nt * 4 + ha) * 32 + dd];
                float lb = attn_l[((size_t)nt * 4 + ha + 2) * 32 + dd];
                float ra = attn_r[((size_t)nt * 4 + ha) * 32 + dd];
                float rb = attn_r[((size_t)nt * 4 + ha + 2) * 32 + dd];
                float pl  = acc[i][0] * la;
                float plb = acc[i][1] * lb;
                float pr  = acc[i][0] * ra;
                float prb = acc[i][1] * rb;
                #pragma unroll
                for (int w = 1; w < 32; w <<= 1) {
                    pl  += __shfl_xor(pl,  w, 64);
                    plb += __shfl_xor(plb, w, 64);
                    pr  += __shfl_xor(pr,  w, 64);
                    prb += __shfl_xor(prb, w, 64);
                }
                if (dd == 0) {
                    el[(size_t)r * 4 + ha]     = pl;
                    el[(size_t)r * 4 + ha + 2] = plb;
                    er[(size_t)r * 4 + ha]     = pr;
                    er[(size_t)r * 4 + ha + 2] = prb;
                }
            }
        }
    }
}

// ---------- 2) ee table: only ET*H distinct values ----------
__global__ void k_ee(const float* __restrict__ W_e, const float* __restrict__ edge_emb,
                     const float* __restrict__ attn_e, float* __restrict__ eet) {
    int t = threadIdx.x;
    if (t >= 8 * 4) return;
    int et = t >> 2, h = t & 3;
    float ee = 0.f;
    for (int f = 0; f < 32; ++f) {
        float acc = 0.f;
        for (int g = 0; g < 32; ++g)
            acc += W_e[((size_t)h * 32 + f) * 32 + g] * edge_emb[et * 32 + g];
        ee += acc * attn_e[((size_t)et * 4 + h) * 32 + f];
    }
    eet[t] = ee * (float)et;
}

// ---------- 3) degree histogram ----------
__global__ void k_deg(const int* __restrict__ dst, int* __restrict__ deg, int ne) {
    int e = blockIdx.x * blockDim.x + threadIdx.x;
    if (e < ne) atomicAdd(deg + dst[e], 1);
}

// ---------- 4) hierarchical exclusive scan: deg -> offs[n+1], cursor ----------
#define SC_ELEMS 1024
__global__ __launch_bounds__(256) void k_scan_sum(const int* __restrict__ deg,
                                                  int* __restrict__ bsum, int n) {
    __shared__ int red[256];
    const int t = threadIdx.x;
    const int base = blockIdx.x * SC_ELEMS;
    int s = 0;
    #pragma unroll
    for (int i = 0; i < 4; ++i) {
        int idx = base + t * 4 + i;
        if (idx < n) s += deg[idx];
    }
    red[t] = s;
    __syncthreads();
    for (int off = 128; off > 0; off >>= 1) {
        if (t < off) red[t] += red[t + off];
        __syncthreads();
    }
    if (t == 0) bsum[blockIdx.x] = red[0];
}

__global__ __launch_bounds__(1024) void k_scan_mid(int* __restrict__ bsum, int nb) {
    __shared__ int sh[1024];
    const int t = threadIdx.x;
    int v = (t < nb) ? bsum[t] : 0;
    sh[t] = v;
    __syncthreads();
    for (int off = 1; off < 1024; off <<= 1) {
        int add = (t >= off) ? sh[t - off] : 0;
        __syncthreads();
        sh[t] += add;
        __syncthreads();
    }
    if (t < nb) bsum[t] = sh[t] - v;   // exclusive
}

__global__ __launch_bounds__(256) void k_scan_out(const int* __restrict__ deg,
                                                  const int* __restrict__ bsum,
                                                  int* __restrict__ offs,
                                                  int* __restrict__ cursor, int n) {
    __shared__ int sh[256];
    const int t = threadIdx.x;
    const int base = blockIdx.x * SC_ELEMS + t * 4;
    int v[4], s = 0;
    #pragma unroll
    for (int i = 0; i < 4; ++i) {
        int idx = base + i;
        v[i] = (idx < n) ? deg[idx] : 0;
        s += v[i];
    }
    sh[t] = s;
    __syncthreads();
    const int mine = s;
    for (int off = 1; off < 256; off <<= 1) {
        int add = (t >= off) ? sh[t - off] : 0;
        __syncthreads();
        sh[t] += add;
        __syncthreads();
    }
    int run = bsum[blockIdx.x] + sh[t] - mine;
    #pragma unroll
    for (int i = 0; i < 4; ++i) {
        int idx = base + i;
        if (idx < n) { offs[idx] = run; cursor[idx] = run; run += v[i]; }
    }
    if (blockIdx.x == gridDim.x - 1 && t == 255) offs[n] = run;
}

// ---------- 5) k_edge: scores + leaky relu + scatter 32B payload into CSR ----------
// payload[pos] = {s0,s1,s2,s3, eid, src, pad, pad}  (8 dwords)
__global__ void k_edge(const int* __restrict__ src, const int* __restrict__ dst,
                       const int* __restrict__ etype, const float* __restrict__ el,
                       const float* __restrict__ er, const float* __restrict__ eet,
                       int* __restrict__ cursor, float* __restrict__ pay, int ne) {
    int e = blockIdx.x * blockDim.x + threadIdx.x;
    if (e >= ne) return;
    int s = src[e], d = dst[e], et = etype[e];
    float4 l = *(const float4*)(el + (size_t)s * 4);
    float4 r = *(const float4*)(er + (size_t)d * 4);
    float4 te = *(const float4*)(eet + (size_t)et * 4);
    float4 v;
    v.x = l.x + r.x + te.x;
    v.y = l.y + r.y + te.y;
    v.z = l.z + r.z + te.z;
    v.w = l.w + r.w + te.w;
    v.x = v.x > 0.f ? v.x : NEG_SLOPE * v.x;
    v.y = v.y > 0.f ? v.y : NEG_SLOPE * v.y;
    v.z = v.z > 0.f ? v.z : NEG_SLOPE * v.z;
    v.w = v.w > 0.f ? v.w : NEG_SLOPE * v.w;
    int pos = atomicAdd(cursor + d, 1);
    *(float4*)(pay + (size_t)pos * 8) = v;
    int2 es; es.x = e; es.y = s;
    *(int2*)(pay + (size_t)pos * 8 + 4) = es;
}

// ---------- 6) per-dst softmax + aggregate: linear staging, parallel reduce ----------
// 128 threads per dst node; thread j owns output column j (head h=j>>5)
#define CHUNK 128
__global__ __launch_bounds__(128) void k_aggfull(const int* __restrict__ offs,
                                                 const float* __restrict__ pay,
                                                 const __hip_bfloat16* __restrict__ fsrcb,
                                                 float* __restrict__ aBuf,
                                                 float* __restrict__ rst) {
    __shared__ int   s_src[CHUNK];
    __shared__ int   s_eid[CHUNK];
    __shared__ float s_sc[4][CHUNK];
    __shared__ float s_p[4][CHUNK];
    __shared__ float s_mr[8];          // m[0..3], rden[4..7]
    const int d = blockIdx.x;
    const int j = threadIdx.x;
    const int h = j >> 5;
    const int b = offs[d], e1 = offs[d + 1];
    const int deg = e1 - b;

    float m = -1e30f, den = 0.f, acc = 0.f;
    for (int c0 = 0; c0 < deg; c0 += CHUNK) {
        const int cn = min(CHUNK, deg - c0);
        if (j < cn) {   // linear payload read (coalesced)
            const float* p8 = pay + (size_t)(b + c0 + j) * 8;
            float4 v = *(const float4*)p8;
            int2 es = *(const int2*)(p8 + 4);
            s_sc[0][j] = v.x; s_sc[1][j] = v.y; s_sc[2][j] = v.z; s_sc[3][j] = v.w;
            s_eid[j] = es.x; s_src[j] = es.y;
        }
        __syncthreads();
        // parallel max within the 32-lane head group
        float mc = -1e30f;
        for (int k = j & 31; k < cn; k += 32) mc = fmaxf(mc, s_sc[h][k]);
        #pragma unroll
        for (int w = 1; w < 32; w <<= 1) mc = fmaxf(mc, __shfl_xor(mc, w, 64));
        mc = fmaxf(mc, m);
        float scale = __expf(m - mc);   // first chunk: exp(-inf)=0; den/acc are 0
        den *= scale; acc *= scale; m = mc;
        if ((j & 31) == 0) s_mr[h] = m;
        __syncthreads();
        // p for this chunk (one edge per thread, all 4 heads)
        if (j < cn) {
            s_p[0][j] = __expf(s_sc[0][j] - s_mr[0]);
            s_p[1][j] = __expf(s_sc[1][j] - s_mr[1]);
            s_p[2][j] = __expf(s_sc[2][j] - s_mr[2]);
            s_p[3][j] = __expf(s_sc[3][j] - s_mr[3]);
        }
        __syncthreads();
        // parallel denom
        float dc = 0.f;
        for (int k = j & 31; k < cn; k += 32) dc += s_p[h][k];
        #pragma unroll
        for (int w = 1; w < 32; w <<= 1) dc += __shfl_xor(dc, w, 64);
        den += dc;
        // gather: p broadcast from LDS, one bf16 load + fma per edge
        #pragma unroll 4
        for (int k = 0; k < cn; ++k) {
            acc = fmaf(s_p[h][k],
                       __bfloat162float(fsrcb[(size_t)s_src[k] * 128 + j]), acc);
        }
        __syncthreads();
    }
    float rden = (den > 0.f) ? 1.f / den : 0.f;
    rst[(size_t)d * 128 + j] = acc * rden;

    if ((j & 31) == 0) s_mr[4 + h] = rden;
    __syncthreads();

    if (deg <= CHUNK) {
        // p in LDS is already vs the final m
        if (j < deg) {
            float4 a;
            a.x = s_p[0][j] * s_mr[4];
            a.y = s_p[1][j] * s_mr[5];
            a.z = s_p[2][j] * s_mr[6];
            a.w = s_p[3][j] * s_mr[7];
            *(float4*)(aBuf + (size_t)s_eid[j] * 4) = a;
        }
    } else {
        for (int k0 = 0; k0 < deg; k0 += CHUNK) {
            int k = k0 + j;
            if (k < deg) {
                const float* p8 = pay + (size_t)(b + k) * 8;
                float4 v = *(const float4*)p8;
                int e = *(const int*)(p8 + 4);
                float4 a;
                a.x = __expf(v.x - s_mr[0]) * s_mr[4];
                a.y = __expf(v.y - s_mr[1]) * s_mr[5];
                a.z = __expf(v.z - s_mr[2]) * s_mr[6];
                a.w = __expf(v.w - s_mr[3]) * s_mr[7];
                *(float4*)(aBuf + (size_t)e * 4) = a;
            }
        }
    }
}

extern "C" void kernel_launch(void* const* d_in, const int* in_sizes, int n_in,
                              void* d_out, int out_size, void* d_ws, size_t ws_size,
                              hipStream_t stream) {
    const float* feat     = (const float*)d_in[0];
    const float* W_fc     = (const float*)d_in[1];
    const float* W_e      = (const float*)d_in[2];
    const float* edge_emb = (const float*)d_in[3];
    const float* attn_l   = (const float*)d_in[4];
    const float* attn_r   = (const float*)d_in[5];
    const float* attn_e   = (const float*)d_in[6];
    const int* src   = (const int*)d_in[7];
    const int* dst   = (const int*)d_in[8];
    const int* etype = (const int*)d_in[9];
    const int* ntype = (const int*)d_in[10];
    const int n  = in_sizes[0] / N_IN;
    const int ne = in_sizes[7];

    // workspace layout
    __hip_bfloat16* fsrcb = (__hip_bfloat16*)d_ws;     // n*128 bf16
    float* pay  = (float*)(fsrcb + (size_t)n * 128);   // ne*8 f (32B payload)
    float* el   = pay + (size_t)ne * 8;                // n*4 f
    float* er   = el + (size_t)n * 4;                  // n*4 f
    float* eet  = er + (size_t)n * 4;                  // 32 f
    int* deg    = (int*)(eet + 32);                    // n i
    int* offs   = deg + n;                             // n+1 i
    int* cursor = offs + n + 1;                        // n i
    int* bsum   = cursor + n;                          // <=1024 i

    float* rst  = (float*)d_out;                       // n*128
    float* aBuf = rst + (size_t)n * 128;               // ne*4 (final a)

    const int nb = (n + SC_ELEMS - 1) / SC_ELEMS;

    hipMemsetAsync(deg, 0, (size_t)n * sizeof(int), stream);

    k_proj<<<512, 256, 0, stream>>>(feat, W_fc, fsrcb, attn_l, attn_r, ntype, el, er, n);
    k_ee<<<1, 32, 0, stream>>>(W_e, edge_emb, attn_e, eet);
    k_deg<<<(ne + 255) / 256, 256, 0, stream>>>(dst, deg, ne);
    k_scan_sum<<<nb, 256, 0, stream>>>(deg, bsum, n);
    k_scan_mid<<<1, 1024, 0, stream>>>(bsum, nb);
    k_scan_out<<<nb, 256, 0, stream>>>(deg, bsum, offs, cursor, n);
    k_edge<<<(ne + 255) / 256, 256, 0, stream>>>(src, dst, etype, el, er, eet, cursor, pay, ne);
    k_aggfull<<<n, 128, 0, stream>>>(offs, pay, fsrcb, aBuf, rst);
}

// Round 8
// 272.006 us; speedup vs baseline: 3.1297x; 1.2246x over previous
//
#include <hip/hip_runtime.h>
#include <hip/hip_bf16.h>

#define NEG_SLOPE 0.2f

typedef __attribute__((ext_vector_type(4))) float f32x4;
typedef __attribute__((ext_vector_type(8))) short s16x8;

__device__ __forceinline__ short f2bf(float x) {
    __hip_bfloat16 h = __float2bfloat16(x);
    return *reinterpret_cast<short*>(&h);
}

// ---------- 1) k_proj: MFMA bf16 GEMM + fused el/er epilogue ----------
// chunk = 64 rows; wave w owns rows [chunk*64 + w*16, +16), all 128 cols.
// W staged once per block in LDS as bf16 [c][k], 16B-granule XOR swizzle.
#define PCHUNK 64
__global__ __launch_bounds__(256) void k_proj(const float* __restrict__ feat,
                                              const float* __restrict__ Wfc,
                                              __hip_bfloat16* __restrict__ fsrcb,
                                              const float* __restrict__ attn_l,
                                              const float* __restrict__ attn_r,
                                              const int* __restrict__ ntype,
                                              float* __restrict__ el,
                                              float* __restrict__ er, int n) {
    __shared__ short Wb[128 * 128];          // 32 KB
    __shared__ float s_al[512], s_ar[512];   // 4 KB attn tables
    const int t = threadIdx.x;
    // stage W: (c,k) -> c*128 + (((k>>3)^(c&7))<<3) + (k&7)
    for (int idx = t; idx < 128 * 128; idx += 256) {
        int c = idx >> 7, k = idx & 127;
        Wb[c * 128 + ((((k >> 3) ^ (c & 7)) << 3) | (k & 7))] = f2bf(Wfc[idx]);
    }
    s_al[t] = attn_l[t]; s_al[t + 256] = attn_l[t + 256];
    s_ar[t] = attn_r[t]; s_ar[t + 256] = attn_r[t + 256];
    __syncthreads();

    const int w   = t >> 6;        // wave 0..3
    const int l   = t & 63;
    const int c16 = l & 15;        // col within 16-frag / D col
    const int g0  = l >> 4;        // k-group 0..3
    const int nchunks = (n + PCHUNK - 1) / PCHUNK;

    for (int chunk = blockIdx.x; chunk < nchunks; chunk += gridDim.x) {
        const int rbase = chunk * PCHUNK + w * 16;
        // A-frags: lane supplies row rbase+c16, k = g0*8 + kq*32 .. +8 (fp32->bf16)
        const float* ap = feat + (size_t)min(rbase + c16, n - 1) * 128;
        s16x8 av[4];
        #pragma unroll
        for (int kq = 0; kq < 4; ++kq) {
            float4 q0 = *(const float4*)(ap + g0 * 8 + kq * 32);
            float4 q1 = *(const float4*)(ap + g0 * 8 + kq * 32 + 4);
            s16x8 a;
            a[0] = f2bf(q0.x); a[1] = f2bf(q0.y); a[2] = f2bf(q0.z); a[3] = f2bf(q0.w);
            a[4] = f2bf(q1.x); a[5] = f2bf(q1.y); a[6] = f2bf(q1.z); a[7] = f2bf(q1.w);
            av[kq] = a;
        }
        f32x4 acc[8];
        #pragma unroll
        for (int f = 0; f < 8; ++f) acc[f] = (f32x4)0.f;
        #pragma unroll
        for (int kq = 0; kq < 4; ++kq) {
            const int g = g0 + kq * 4;
            #pragma unroll
            for (int f = 0; f < 8; ++f) {
                const int c = f * 16 + c16;     // B col = output col
                const s16x8 bv = *(const s16x8*)&Wb[c * 128 + ((g ^ (c & 7)) << 3)];
                acc[f] = __builtin_amdgcn_mfma_f32_16x16x32_bf16(av[kq], bv, acc[f], 0, 0, 0);
            }
        }
        // D layout: col = c16 + f*16, row = rbase + g0*4 + reg
        #pragma unroll
        for (int reg = 0; reg < 4; ++reg) {
            const int rr = rbase + g0 * 4 + reg;
            const bool ok = rr < n;
            if (ok) {
                #pragma unroll
                for (int f = 0; f < 8; ++f)
                    fsrcb[(size_t)rr * 128 + f * 16 + c16] = __float2bfloat16(acc[f][reg]);
            }
            // fused el/er: head h covers frags 2h,2h+1; lane's dims d = c16, 16+c16
            const int nt = ntype[min(rr, n - 1)];
            const float* alp = s_al + nt * 128;
            const float* arp = s_ar + nt * 128;
            float pe[4], pr[4];
            #pragma unroll
            for (int h = 0; h < 4; ++h) {
                float d0 = acc[2 * h][reg], d1 = acc[2 * h + 1][reg];
                pe[h] = d0 * alp[h * 32 + c16] + d1 * alp[h * 32 + 16 + c16];
                pr[h] = d0 * arp[h * 32 + c16] + d1 * arp[h * 32 + 16 + c16];
            }
            #pragma unroll
            for (int msk = 1; msk < 16; msk <<= 1) {
                #pragma unroll
                for (int h = 0; h < 4; ++h) {
                    pe[h] += __shfl_xor(pe[h], msk, 64);
                    pr[h] += __shfl_xor(pr[h], msk, 64);
                }
            }
            if (c16 == 0 && ok) {
                float4 e4; e4.x = pe[0]; e4.y = pe[1]; e4.z = pe[2]; e4.w = pe[3];
                float4 r4; r4.x = pr[0]; r4.y = pr[1]; r4.z = pr[2]; r4.w = pr[3];
                *(float4*)(el + (size_t)rr * 4) = e4;
                *(float4*)(er + (size_t)rr * 4) = r4;
            }
        }
    }
}

// ---------- 2) ee table: only ET*H distinct values ----------
__global__ void k_ee(const float* __restrict__ W_e, const float* __restrict__ edge_emb,
                     const float* __restrict__ attn_e, float* __restrict__ eet) {
    int t = threadIdx.x;
    if (t >= 8 * 4) return;
    int et = t >> 2, h = t & 3;
    float ee = 0.f;
    for (int f = 0; f < 32; ++f) {
        float acc = 0.f;
        for (int g = 0; g < 32; ++g)
            acc += W_e[((size_t)h * 32 + f) * 32 + g] * edge_emb[et * 32 + g];
        ee += acc * attn_e[((size_t)et * 4 + h) * 32 + f];
    }
    eet[t] = ee * (float)et;
}

// ---------- 3) degree histogram ----------
__global__ void k_deg(const int* __restrict__ dst, int* __restrict__ deg, int ne) {
    int e = blockIdx.x * blockDim.x + threadIdx.x;
    if (e < ne) atomicAdd(deg + dst[e], 1);
}

// ---------- 4) hierarchical exclusive scan: deg -> offs[n+1], cursor ----------
#define SC_ELEMS 1024
__global__ __launch_bounds__(256) void k_scan_sum(const int* __restrict__ deg,
                                                  int* __restrict__ bsum, int n) {
    __shared__ int red[256];
    const int t = threadIdx.x;
    const int base = blockIdx.x * SC_ELEMS;
    int s = 0;
    #pragma unroll
    for (int i = 0; i < 4; ++i) {
        int idx = base + t * 4 + i;
        if (idx < n) s += deg[idx];
    }
    red[t] = s;
    __syncthreads();
    for (int off = 128; off > 0; off >>= 1) {
        if (t < off) red[t] += red[t + off];
        __syncthreads();
    }
    if (t == 0) bsum[blockIdx.x] = red[0];
}

__global__ __launch_bounds__(1024) void k_scan_mid(int* __restrict__ bsum, int nb) {
    __shared__ int sh[1024];
    const int t = threadIdx.x;
    int v = (t < nb) ? bsum[t] : 0;
    sh[t] = v;
    __syncthreads();
    for (int off = 1; off < 1024; off <<= 1) {
        int add = (t >= off) ? sh[t - off] : 0;
        __syncthreads();
        sh[t] += add;
        __syncthreads();
    }
    if (t < nb) bsum[t] = sh[t] - v;   // exclusive
}

__global__ __launch_bounds__(256) void k_scan_out(const int* __restrict__ deg,
                                                  const int* __restrict__ bsum,
                                                  int* __restrict__ offs,
                                                  int* __restrict__ cursor, int n) {
    __shared__ int sh[256];
    const int t = threadIdx.x;
    const int base = blockIdx.x * SC_ELEMS + t * 4;
    int v[4], s = 0;
    #pragma unroll
    for (int i = 0; i < 4; ++i) {
        int idx = base + i;
        v[i] = (idx < n) ? deg[idx] : 0;
        s += v[i];
    }
    sh[t] = s;
    __syncthreads();
    const int mine = s;
    for (int off = 1; off < 256; off <<= 1) {
        int add = (t >= off) ? sh[t - off] : 0;
        __syncthreads();
        sh[t] += add;
        __syncthreads();
    }
    int run = bsum[blockIdx.x] + sh[t] - mine;
    #pragma unroll
    for (int i = 0; i < 4; ++i) {
        int idx = base + i;
        if (idx < n) { offs[idx] = run; cursor[idx] = run; run += v[i]; }
    }
    if (blockIdx.x == gridDim.x - 1 && t == 255) offs[n] = run;
}

// ---------- 5) k_edge: scores + leaky relu + scatter 32B payload into CSR ----------
__global__ void k_edge(const int* __restrict__ src, const int* __restrict__ dst,
                       const int* __restrict__ etype, const float* __restrict__ el,
                       const float* __restrict__ er, const float* __restrict__ eet,
                       int* __restrict__ cursor, float* __restrict__ pay, int ne) {
    int e = blockIdx.x * blockDim.x + threadIdx.x;
    if (e >= ne) return;
    int s = src[e], d = dst[e], et = etype[e];
    float4 l = *(const float4*)(el + (size_t)s * 4);
    float4 r = *(const float4*)(er + (size_t)d * 4);
    float4 te = *(const float4*)(eet + (size_t)et * 4);
    float4 v;
    v.x = l.x + r.x + te.x;
    v.y = l.y + r.y + te.y;
    v.z = l.z + r.z + te.z;
    v.w = l.w + r.w + te.w;
    v.x = v.x > 0.f ? v.x : NEG_SLOPE * v.x;
    v.y = v.y > 0.f ? v.y : NEG_SLOPE * v.y;
    v.z = v.z > 0.f ? v.z : NEG_SLOPE * v.z;
    v.w = v.w > 0.f ? v.w : NEG_SLOPE * v.w;
    int pos = atomicAdd(cursor + d, 1);
    *(float4*)(pay + (size_t)pos * 8) = v;
    int2 es; es.x = e; es.y = s;
    *(int2*)(pay + (size_t)pos * 8 + 4) = es;
}

// ---------- 6) per-dst softmax + aggregate ----------
#define CHUNK 128
__global__ __launch_bounds__(128) void k_aggfull(const int* __restrict__ offs,
                                                 const float* __restrict__ pay,
                                                 const __hip_bfloat16* __restrict__ fsrcb,
                                                 float* __restrict__ aBuf,
                                                 float* __restrict__ rst) {
    __shared__ int   s_src[CHUNK];
    __shared__ int   s_eid[CHUNK];
    __shared__ float s_sc[4][CHUNK];
    __shared__ float s_p[4][CHUNK];
    __shared__ float s_mr[8];          // m[0..3], rden[4..7]
    const int d = blockIdx.x;
    const int j = threadIdx.x;
    const int h = j >> 5;
    const int b = offs[d], e1 = offs[d + 1];
    const int deg = e1 - b;

    float m = -1e30f, den = 0.f, acc = 0.f;
    for (int c0 = 0; c0 < deg; c0 += CHUNK) {
        const int cn = min(CHUNK, deg - c0);
        if (j < cn) {   // linear payload read (coalesced)
            const float* p8 = pay + (size_t)(b + c0 + j) * 8;
            float4 v = *(const float4*)p8;
            int2 es = *(const int2*)(p8 + 4);
            s_sc[0][j] = v.x; s_sc[1][j] = v.y; s_sc[2][j] = v.z; s_sc[3][j] = v.w;
            s_eid[j] = es.x; s_src[j] = es.y;
        }
        __syncthreads();
        float mc = -1e30f;
        for (int k = j & 31; k < cn; k += 32) mc = fmaxf(mc, s_sc[h][k]);
        #pragma unroll
        for (int w = 1; w < 32; w <<= 1) mc = fmaxf(mc, __shfl_xor(mc, w, 64));
        mc = fmaxf(mc, m);
        float scale = __expf(m - mc);
        den *= scale; acc *= scale; m = mc;
        if ((j & 31) == 0) s_mr[h] = m;
        __syncthreads();
        if (j < cn) {
            s_p[0][j] = __expf(s_sc[0][j] - s_mr[0]);
            s_p[1][j] = __expf(s_sc[1][j] - s_mr[1]);
            s_p[2][j] = __expf(s_sc[2][j] - s_mr[2]);
            s_p[3][j] = __expf(s_sc[3][j] - s_mr[3]);
        }
        __syncthreads();
        float dc = 0.f;
        for (int k = j & 31; k < cn; k += 32) dc += s_p[h][k];
        #pragma unroll
        for (int w = 1; w < 32; w <<= 1) dc += __shfl_xor(dc, w, 64);
        den += dc;
        #pragma unroll 4
        for (int k = 0; k < cn; ++k) {
            acc = fmaf(s_p[h][k],
                       __bfloat162float(fsrcb[(size_t)s_src[k] * 128 + j]), acc);
        }
        __syncthreads();
    }
    float rden = (den > 0.f) ? 1.f / den : 0.f;
    rst[(size_t)d * 128 + j] = acc * rden;

    if ((j & 31) == 0) s_mr[4 + h] = rden;
    __syncthreads();

    if (deg <= CHUNK) {
        if (j < deg) {
            float4 a;
            a.x = s_p[0][j] * s_mr[4];
            a.y = s_p[1][j] * s_mr[5];
            a.z = s_p[2][j] * s_mr[6];
            a.w = s_p[3][j] * s_mr[7];
            *(float4*)(aBuf + (size_t)s_eid[j] * 4) = a;
        }
    } else {
        for (int k0 = 0; k0 < deg; k0 += CHUNK) {
            int k = k0 + j;
            if (k < deg) {
                const float* p8 = pay + (size_t)(b + k) * 8;
                float4 v = *(const float4*)p8;
                int e = *(const int*)(p8 + 4);
                float4 a;
                a.x = __expf(v.x - s_mr[0]) * s_mr[4];
                a.y = __expf(v.y - s_mr[1]) * s_mr[5];
                a.z = __expf(v.z - s_mr[2]) * s_mr[6];
                a.w = __expf(v.w - s_mr[3]) * s_mr[7];
                *(float4*)(aBuf + (size_t)e * 4) = a;
            }
        }
    }
}

extern "C" void kernel_launch(void* const* d_in, const int* in_sizes, int n_in,
                              void* d_out, int out_size, void* d_ws, size_t ws_size,
                              hipStream_t stream) {
    const float* feat     = (const float*)d_in[0];
    const float* W_fc     = (const float*)d_in[1];
    const float* W_e      = (const float*)d_in[2];
    const float* edge_emb = (const float*)d_in[3];
    const float* attn_l   = (const float*)d_in[4];
    const float* attn_r   = (const float*)d_in[5];
    const float* attn_e   = (const float*)d_in[6];
    const int* src   = (const int*)d_in[7];
    const int* dst   = (const int*)d_in[8];
    const int* etype = (const int*)d_in[9];
    const int* ntype = (const int*)d_in[10];
    const int n  = in_sizes[0] / 128;
    const int ne = in_sizes[7];

    // workspace layout
    __hip_bfloat16* fsrcb = (__hip_bfloat16*)d_ws;     // n*128 bf16
    float* pay  = (float*)(fsrcb + (size_t)n * 128);   // ne*8 f (32B payload)
    float* el   = pay + (size_t)ne * 8;                // n*4 f
    float* er   = el + (size_t)n * 4;                  // n*4 f
    float* eet  = er + (size_t)n * 4;                  // 32 f
    int* deg    = (int*)(eet + 32);                    // n i
    int* offs   = deg + n;                             // n+1 i
    int* cursor = offs + n + 1;                        // n i
    int* bsum   = cursor + n;                          // <=1024 i

    float* rst  = (float*)d_out;                       // n*128
    float* aBuf = rst + (size_t)n * 128;               // ne*4 (final a)

    const int nb = (n + SC_ELEMS - 1) / SC_ELEMS;

    hipMemsetAsync(deg, 0, (size_t)n * sizeof(int), stream);

    k_proj<<<512, 256, 0, stream>>>(feat, W_fc, fsrcb, attn_l, attn_r, ntype, el, er, n);
    k_ee<<<1, 32, 0, stream>>>(W_e, edge_emb, attn_e, eet);
    k_deg<<<(ne + 255) / 256, 256, 0, stream>>>(dst, deg, ne);
    k_scan_sum<<<nb, 256, 0, stream>>>(deg, bsum, n);
    k_scan_mid<<<1, 1024, 0, stream>>>(bsum, nb);
    k_scan_out<<<nb, 256, 0, stream>>>(deg, bsum, offs, cursor, n);
    k_edge<<<(ne + 255) / 256, 256, 0, stream>>>(src, dst, etype, el, er, eet, cursor, pay, ne);
    k_aggfull<<<n, 128, 0, stream>>>(offs, pay, fsrcb, aBuf, rst);
}